// Round 8
// baseline (304.674 us; speedup 1.0000x reference)
//
#include <hip/hip_runtime.h>
#include <stdint.h>

// RobertaSelfAttention: B=4, S=2048, HID=1024, NH=16, HD=64. fp32 in/out.
// R8: attn_k barrier-free — K/V frags loaded DIRECT global->register
// (L2-resident, dwordx4), no LDS staging, no __syncthreads in main loop.
// Tests whether the invariant ~101us wall (R3/R4/R7) is the barrier-locked
// staging structure (expect ~60us) or transcendental throughput (no change).

typedef float f32x4 __attribute__((ext_vector_type(4)));
typedef float f32x16 __attribute__((ext_vector_type(16)));
typedef __bf16 bf16x8 __attribute__((ext_vector_type(8)));
typedef unsigned short ushort_t;
typedef uint32_t u32;

#define MFMA16(a, b, c) __builtin_amdgcn_mfma_f32_16x16x32_bf16(a, b, c, 0, 0, 0)
#define MFMA32(a, b, c) __builtin_amdgcn_mfma_f32_32x32x16_bf16(a, b, c, 0, 0, 0)

__device__ __forceinline__ ushort_t f2b(float f) {
    union { float f; uint32_t u; } x{f};
    uint32_t r = (x.u + 0x7fffu + ((x.u >> 16) & 1u)) >> 16;  // RNE
    return (ushort_t)r;
}

__device__ __forceinline__ float fexp2(float x) {
#if __has_builtin(__builtin_amdgcn_exp2f)
    return __builtin_amdgcn_exp2f(x);
#else
    return exp2f(x);
#endif
}

// pack {bf16(e) lo16, bf16(o) hi16} by byte-perm truncation (e,o > 0)
__device__ __forceinline__ u32 pkpair(float e, float o) {
    union { float f; u32 u; } xe{e}, xo{o};
    return __builtin_amdgcn_perm(xo.u, xe.u, 0x07060302u);
}

__device__ __forceinline__ bf16x8 mk8(u32 a, u32 b, u32 c, u32 d) {
    union { u32 u[4]; bf16x8 v; } x;
    x.u[0] = a; x.u[1] = b; x.u[2] = c; x.u[3] = d;
    return x.v;
}

__device__ __forceinline__ void gld_lds16(const void* g, void* l) {
    __builtin_amdgcn_global_load_lds(
        (const __attribute__((address_space(1))) unsigned int*)g,
        (__attribute__((address_space(3))) unsigned int*)l, 16, 0, 0);
}

// ---------------- fp32 -> bf16 convert: hidden (8M) + Wq/Wk/Wv (3x1M) -------
__global__ __launch_bounds__(256) void convert_k(
    const float* __restrict__ hs, const float* __restrict__ wq,
    const float* __restrict__ wk, const float* __restrict__ wv,
    ushort_t* __restrict__ hs_b, ushort_t* __restrict__ w_b) {
    size_t c = (size_t)blockIdx.x * 256 + threadIdx.x;
    size_t i = c * 8;
    const size_t NHS = (size_t)8192 * 1024;
    const float* src;
    ushort_t* dst;
    if (i < NHS) { src = hs + i; dst = hs_b + i; }
    else {
        size_t j = i - NHS;
        int w = (int)(j >> 20);
        size_t o = j & ((1u << 20) - 1);
        src = (w == 0 ? wq : (w == 1 ? wk : wv)) + o;
        dst = w_b + ((size_t)w << 20) + o;
    }
    float4 a = *(const float4*)src;
    float4 b = *(const float4*)(src + 4);
    uint32_t p0 = (uint32_t)f2b(a.x) | ((uint32_t)f2b(a.y) << 16);
    uint32_t p1 = (uint32_t)f2b(a.z) | ((uint32_t)f2b(a.w) << 16);
    uint32_t p2 = (uint32_t)f2b(b.x) | ((uint32_t)f2b(b.y) << 16);
    uint32_t p3 = (uint32_t)f2b(b.z) | ((uint32_t)f2b(b.w) << 16);
    uint4 v{p0, p1, p2, p3};
    *(uint4*)dst = v;
}

// ---------------- QKV projection GEMM (unchanged from R7) ----------------
__global__ __launch_bounds__(256, 4) void qkv_gemm(
    const ushort_t* __restrict__ Ab, const ushort_t* __restrict__ Wb,
    const float* __restrict__ bq, const float* __restrict__ bk,
    const float* __restrict__ bv, ushort_t* __restrict__ q_ws,
    ushort_t* __restrict__ k_ws, ushort_t* __restrict__ vt_ws) {
    __shared__ __align__(16) char smem_raw[128 * 136 * 2];  // 34816 B
    ushort_t* At = (ushort_t*)smem_raw;        // [128][64]
    ushort_t* Bt = At + 128 * 64;              // [128][64]
    ushort_t* Ct = (ushort_t*)smem_raw;        // [128][stride 136] overlay
    int which = blockIdx.z;
    const ushort_t* W = Wb + ((size_t)which << 20);
    int m0 = blockIdx.y * 128, n0 = blockIdx.x * 128;
    int t = threadIdx.x, lane = t & 63, wave = t >> 6;
    int quad = lane >> 4, l16 = lane & 15;
    int wr = (wave >> 1) * 64, wc = (wave & 1) * 64;
    f32x4 acc[4][4] = {};
    for (int k0 = 0; k0 < 1024; k0 += 64) {
        for (int r = 0; r < 4; r++) {
            int idx = r * 256 + t;
            int row = idx >> 3, co = (idx & 7) * 8;
            gld_lds16(Ab + (size_t)(m0 + row) * 1024 + k0 + co, At + idx * 8);
            gld_lds16(W + (size_t)(n0 + row) * 1024 + k0 + co, Bt + idx * 8);
        }
        asm volatile("s_waitcnt vmcnt(0)" ::: "memory");
        __syncthreads();
        for (int kk = 0; kk < 2; kk++) {
            bf16x8 af[4], bf[4];
            for (int i = 0; i < 4; i++)
                af[i] = *(const bf16x8*)(At + (wr + i * 16 + l16) * 64 + kk * 32 + quad * 8);
            for (int j = 0; j < 4; j++)
                bf[j] = *(const bf16x8*)(Bt + (wc + j * 16 + l16) * 64 + kk * 32 + quad * 8);
            for (int i = 0; i < 4; i++)
                for (int j = 0; j < 4; j++)
                    acc[i][j] = MFMA16(af[i], bf[j], acc[i][j]);
        }
        __syncthreads();
    }
    const float* bias = which == 0 ? bq : (which == 1 ? bk : bv);
    float sc = which == 0 ? (0.125f * 1.44269504f) : 1.0f;  // 1/sqrt(HD)*log2e
    if (which == 2) {
        for (int j = 0; j < 4; j++) {
            float bias_v = bias[n0 + wc + j * 16 + l16];
            for (int i = 0; i < 4; i++) {
                ushort4 pk;
                pk.x = f2b(acc[i][j].x + bias_v);
                pk.y = f2b(acc[i][j].y + bias_v);
                pk.z = f2b(acc[i][j].z + bias_v);
                pk.w = f2b(acc[i][j].w + bias_v);
                *(ushort4*)(Ct + (wc + j * 16 + l16) * 136 + wr + i * 16 + quad * 4) = pk;
            }
        }
    } else {
        for (int j = 0; j < 4; j++) {
            float bias_v = bias[n0 + wc + j * 16 + l16];
            int col = wc + j * 16 + l16;
            for (int i = 0; i < 4; i++) {
                int rb = wr + i * 16 + quad * 4;
                Ct[(rb + 0) * 136 + col] = f2b((acc[i][j].x + bias_v) * sc);
                Ct[(rb + 1) * 136 + col] = f2b((acc[i][j].y + bias_v) * sc);
                Ct[(rb + 2) * 136 + col] = f2b((acc[i][j].z + bias_v) * sc);
                Ct[(rb + 3) * 136 + col] = f2b((acc[i][j].w + bias_v) * sc);
            }
        }
    }
    __syncthreads();
    for (int r = 0; r < 8; r++) {
        int idx = r * 256 + t;
        int row = idx >> 4, c8 = (idx & 15) * 8;
        uint4 val = *(const uint4*)(Ct + row * 136 + c8);
        if (which == 2) {
            int col = n0 + row, h = col >> 6, d = col & 63;
            int tok = m0 + c8, b = tok >> 11, s = tok & 2047;
            *(uint4*)(vt_ws + ((size_t)(b * 16 + h) * 64 + d) * 2048 + s) = val;
        } else {
            int tok = m0 + row, b = tok >> 11, s = tok & 2047;
            int col = n0 + c8, h = col >> 6, d = col & 63;
            ushort_t* base = which == 0 ? q_ws : k_ws;
            *(uint4*)(base + ((size_t)(b * 16 + h) * 2048 + s) * 64 + d) = val;
        }
    }
}

// ---------------- flash attention: barrier-free, register-direct K/V -------
// Wave: 64 q (2 groups of 32), 64 keys/tile. K/V frags loaded straight from
// global (L2-resident). No LDS staging, no main-loop barriers — waves are
// fully independent; compiler pipelines loads across the exp phase.
__global__ __launch_bounds__(256, 2) void attn_k(
    const ushort_t* __restrict__ q_ws, const ushort_t* __restrict__ k_ws,
    const ushort_t* __restrict__ vt_ws, const float* __restrict__ mask,
    float* __restrict__ out) {
    __shared__ __align__(16) float Ow[128 * 65];  // epilogue transpose only

    int bh = blockIdx.y, b = bh >> 4, h = bh & 15;
    int q0 = blockIdx.x * 256;
    int t = threadIdx.x, lane = t & 63, w = t >> 6;
    int l31 = lane & 31, hi = lane >> 5;
    bool h0 = (hi == 0);
    const ushort_t* Q = q_ws + (size_t)bh * 2048 * 64;
    const ushort_t* K = k_ws + (size_t)bh * 2048 * 64;
    const ushort_t* Vt = vt_ws + (size_t)bh * 64 * 2048;
    const float* mrow = mask + b * 2048;

    bf16x8 qf[2][4];
#pragma unroll
    for (int qg = 0; qg < 2; qg++)
#pragma unroll
        for (int cs = 0; cs < 4; cs++)
            qf[qg][cs] = *(const bf16x8*)(
                Q + (size_t)(q0 + w * 64 + qg * 32 + l31) * 64 + cs * 16 + hi * 8);

    f32x16 o00 = {}, o01 = {}, o10 = {}, o11 = {};
    float rs0 = 0.f, rs1 = 0.f;

    const ushort_t* Krow0 = K + (size_t)l31 * 64 + hi * 8;         // key l31
    const ushort_t* Krow1 = K + (size_t)(32 + l31) * 64 + hi * 8;  // key 32+l31
    const ushort_t* Vrow0 = Vt + (size_t)l31 * 2048 + hi * 8;      // d = l31
    const ushort_t* Vrow1 = Vt + (size_t)(32 + l31) * 2048 + hi * 8;

    for (int t0 = 0; t0 < 2048; t0 += 64) {
        // K frags direct from global (row stride 64 shorts = 128B)
        bf16x8 k0[4], k1[4];
#pragma unroll
        for (int cs = 0; cs < 4; cs++) {
            k0[cs] = *(const bf16x8*)(Krow0 + (size_t)t0 * 64 + cs * 16);
            k1[cs] = *(const bf16x8*)(Krow1 + (size_t)t0 * 64 + cs * 16);
        }
        // S^T = K · Q^T for both q-groups (K frags shared)
        f32x16 s00 = {}, s01 = {}, s10 = {}, s11 = {};
#pragma unroll
        for (int cs = 0; cs < 4; cs++) {
            s00 = MFMA32(k0[cs], qf[0][cs], s00);
            s01 = MFMA32(k1[cs], qf[0][cs], s01);
            s10 = MFMA32(k0[cs], qf[1][cs], s10);
            s11 = MFMA32(k1[cs], qf[1][cs], s11);
        }
        // V frags issued now; latency hidden behind exp/pack/shfl below
        bf16x8 v0[4], v1[4];
#pragma unroll
        for (int cs = 0; cs < 4; cs++) {
            v0[cs] = *(const bf16x8*)(Vrow0 + t0 + cs * 16);
            v1[cs] = *(const bf16x8*)(Vrow1 + t0 + cs * 16);
        }
        // exp2 + pack + P^T B-frags per q-group (mask from global, L1-hot)
        bf16x8 pfr[2][4];
#pragma unroll
        for (int qg = 0; qg < 2; qg++) {
            const f32x16& sa = qg ? s10 : s00;
            const f32x16& sb = qg ? s11 : s01;
            u32 pa[8], pb[8];
            float rst = 0.f;
#pragma unroll
            for (int i = 0; i < 4; i++) {
                float4 bm = *(const float4*)(mrow + t0 + 8 * i + 4 * hi);
                float e0 = fexp2(fmaf(bm.x, 1.44269504f, sa[4 * i + 0]));
                float e1 = fexp2(fmaf(bm.y, 1.44269504f, sa[4 * i + 1]));
                float e2 = fexp2(fmaf(bm.z, 1.44269504f, sa[4 * i + 2]));
                float e3 = fexp2(fmaf(bm.w, 1.44269504f, sa[4 * i + 3]));
                rst += (e0 + e1) + (e2 + e3);
                pa[2 * i] = pkpair(e0, e1);
                pa[2 * i + 1] = pkpair(e2, e3);
            }
#pragma unroll
            for (int i = 0; i < 4; i++) {
                float4 bm = *(const float4*)(mrow + t0 + 32 + 8 * i + 4 * hi);
                float e0 = fexp2(fmaf(bm.x, 1.44269504f, sb[4 * i + 0]));
                float e1 = fexp2(fmaf(bm.y, 1.44269504f, sb[4 * i + 1]));
                float e2 = fexp2(fmaf(bm.z, 1.44269504f, sb[4 * i + 2]));
                float e3 = fexp2(fmaf(bm.w, 1.44269504f, sb[4 * i + 3]));
                rst += (e0 + e1) + (e2 + e3);
                pb[2 * i] = pkpair(e0, e1);
                pb[2 * i + 1] = pkpair(e2, e3);
            }
            if (qg == 0) rs0 += rst; else rs1 += rst;
#pragma unroll
            for (int g = 0; g < 4; g++) {
                const u32* aa = (g < 2) ? pa : pb;
                int base = (g & 1) * 4;
                u32 y0 = h0 ? aa[base + 2] : aa[base + 0];
                u32 y1 = h0 ? aa[base + 3] : aa[base + 1];
                u32 sy0 = (u32)__shfl_xor((int)y0, 32, 64);
                u32 sy1 = (u32)__shfl_xor((int)y1, 32, 64);
                pfr[qg][g] = mk8(h0 ? aa[base + 0] : sy0, h0 ? aa[base + 1] : sy1,
                                 h0 ? sy0 : aa[base + 2], h0 ? sy1 : aa[base + 3]);
            }
        }
        // O^T += V^T · P^T for both q-groups (V frags shared)
#pragma unroll
        for (int cs = 0; cs < 4; cs++) {
            o00 = MFMA32(v0[cs], pfr[0][cs], o00);
            o01 = MFMA32(v1[cs], pfr[0][cs], o01);
            o10 = MFMA32(v0[cs], pfr[1][cs], o10);
            o11 = MFMA32(v1[cs], pfr[1][cs], o11);
        }
    }
    rs0 += __shfl_xor(rs0, 32, 64);
    rs1 += __shfl_xor(rs1, 32, 64);
    float inv0 = 1.f / rs0, inv1 = 1.f / rs1;
    // epilogue: per q-group, O^T -> LDS transpose -> coalesced f32x4 stores
#pragma unroll
    for (int qg = 0; qg < 2; qg++) {
        float inv = qg ? inv1 : inv0;
        const f32x16& a0 = qg ? o10 : o00;
        const f32x16& a1 = qg ? o11 : o01;
#pragma unroll
        for (int g = 0; g < 4; g++) {
            f32x4 c0, c1;
#pragma unroll
            for (int r = 0; r < 4; r++) {
                c0[r] = a0[4 * g + r] * inv;
                c1[r] = a1[4 * g + r] * inv;
            }
            *(f32x4*)(Ow + (w * 32 + l31) * 65 + 8 * g + 4 * hi) = c0;
            *(f32x4*)(Ow + (w * 32 + l31) * 65 + 32 + 8 * g + 4 * hi) = c1;
        }
        __syncthreads();
#pragma unroll
        for (int cc = 0; cc < 8; cc++) {
            int c = cc * 256 + t;
            int row = c >> 4, seg = (c & 15) * 4;
            f32x4 vv = *(const f32x4*)(Ow + row * 65 + seg);
            int ql = (row >> 5) * 64 + qg * 32 + (row & 31);
            *(f32x4*)(out + ((size_t)(b * 2048 + q0 + ql)) * 1024 + h * 64 + seg) = vv;
        }
        __syncthreads();
    }
}

extern "C" void kernel_launch(void* const* d_in, const int* in_sizes, int n_in,
                              void* d_out, int out_size, void* d_ws, size_t ws_size,
                              hipStream_t stream) {
    const float* hs = (const float*)d_in[0];
    const float* mask = (const float*)d_in[1];
    const float* wq = (const float*)d_in[2];
    const float* bq = (const float*)d_in[3];
    const float* wk = (const float*)d_in[4];
    const float* bk = (const float*)d_in[5];
    const float* wv = (const float*)d_in[6];
    const float* bv = (const float*)d_in[7];
    float* out = (float*)d_out;
    char* ws = (char*)d_ws;
    ushort_t* hs_b = (ushort_t*)ws;
    ushort_t* w_b = (ushort_t*)(ws + 16777216);
    ushort_t* q_ws = (ushort_t*)(ws + 23068672);
    ushort_t* k_ws = (ushort_t*)(ws + 39845888);
    ushort_t* vt_ws = (ushort_t*)(ws + 56623104);

    convert_k<<<5632, 256, 0, stream>>>(hs, wq, wk, wv, hs_b, w_b);
    qkv_gemm<<<dim3(8, 64, 3), 256, 0, stream>>>(hs_b, w_b, bq, bk, bv, q_ws, k_ws, vt_ws);
    attn_k<<<dim3(8, 64), 256, 0, stream>>>(q_ws, k_ws, vt_ws, mask, out);
}

// Round 9
// 280.934 us; speedup vs baseline: 1.0845x; 1.0845x over previous
//
#include <hip/hip_runtime.h>
#include <stdint.h>

// RobertaSelfAttention: B=4, S=2048, HID=1024, NH=16, HD=64. fp32 in/out.
// R9: attn_k — two-tile ILP per barrier round. Evidence: R3/R4/R7 all take
// ~7650cyc/tile-round vs ~1300cyc pipe demand (80% stall) because the
// per-tile barrier puts every wave in the same phase (LDS burst / MFMA /
// exp burst serialize). Interleaving two independent 64-key tile chains in
// one wave overlaps tile A's exp with tile B's MFMA/LDS. Quad-buffered
// staging (R7 single-barrier prefetch retained), mask in LDS.

typedef float f32x4 __attribute__((ext_vector_type(4)));
typedef float f32x16 __attribute__((ext_vector_type(16)));
typedef __bf16 bf16x8 __attribute__((ext_vector_type(8)));
typedef unsigned short ushort_t;
typedef uint32_t u32;

#define MFMA16(a, b, c) __builtin_amdgcn_mfma_f32_16x16x32_bf16(a, b, c, 0, 0, 0)
#define MFMA32(a, b, c) __builtin_amdgcn_mfma_f32_32x32x16_bf16(a, b, c, 0, 0, 0)

__device__ __forceinline__ ushort_t f2b(float f) {
    union { float f; uint32_t u; } x{f};
    uint32_t r = (x.u + 0x7fffu + ((x.u >> 16) & 1u)) >> 16;  // RNE
    return (ushort_t)r;
}

__device__ __forceinline__ float fexp2(float x) {
#if __has_builtin(__builtin_amdgcn_exp2f)
    return __builtin_amdgcn_exp2f(x);
#else
    return exp2f(x);
#endif
}

// pack {bf16(e) lo16, bf16(o) hi16} by byte-perm truncation (e,o > 0)
__device__ __forceinline__ u32 pkpair(float e, float o) {
    union { float f; u32 u; } xe{e}, xo{o};
    return __builtin_amdgcn_perm(xo.u, xe.u, 0x07060302u);
}

__device__ __forceinline__ bf16x8 mk8(u32 a, u32 b, u32 c, u32 d) {
    union { u32 u[4]; bf16x8 v; } x;
    x.u[0] = a; x.u[1] = b; x.u[2] = c; x.u[3] = d;
    return x.v;
}

__device__ __forceinline__ void gld_lds16(const void* g, void* l) {
    __builtin_amdgcn_global_load_lds(
        (const __attribute__((address_space(1))) unsigned int*)g,
        (__attribute__((address_space(3))) unsigned int*)l, 16, 0, 0);
}

// ---------------- fp32 -> bf16 convert: hidden (8M) + Wq/Wk/Wv (3x1M) -------
__global__ __launch_bounds__(256) void convert_k(
    const float* __restrict__ hs, const float* __restrict__ wq,
    const float* __restrict__ wk, const float* __restrict__ wv,
    ushort_t* __restrict__ hs_b, ushort_t* __restrict__ w_b) {
    size_t c = (size_t)blockIdx.x * 256 + threadIdx.x;
    size_t i = c * 8;
    const size_t NHS = (size_t)8192 * 1024;
    const float* src;
    ushort_t* dst;
    if (i < NHS) { src = hs + i; dst = hs_b + i; }
    else {
        size_t j = i - NHS;
        int w = (int)(j >> 20);
        size_t o = j & ((1u << 20) - 1);
        src = (w == 0 ? wq : (w == 1 ? wk : wv)) + o;
        dst = w_b + ((size_t)w << 20) + o;
    }
    float4 a = *(const float4*)src;
    float4 b = *(const float4*)(src + 4);
    uint32_t p0 = (uint32_t)f2b(a.x) | ((uint32_t)f2b(a.y) << 16);
    uint32_t p1 = (uint32_t)f2b(a.z) | ((uint32_t)f2b(a.w) << 16);
    uint32_t p2 = (uint32_t)f2b(b.x) | ((uint32_t)f2b(b.y) << 16);
    uint32_t p3 = (uint32_t)f2b(b.z) | ((uint32_t)f2b(b.w) << 16);
    uint4 v{p0, p1, p2, p3};
    *(uint4*)dst = v;
}

// ---------------- QKV projection GEMM (unchanged from R7) ----------------
__global__ __launch_bounds__(256, 4) void qkv_gemm(
    const ushort_t* __restrict__ Ab, const ushort_t* __restrict__ Wb,
    const float* __restrict__ bq, const float* __restrict__ bk,
    const float* __restrict__ bv, ushort_t* __restrict__ q_ws,
    ushort_t* __restrict__ k_ws, ushort_t* __restrict__ vt_ws) {
    __shared__ __align__(16) char smem_raw[128 * 136 * 2];  // 34816 B
    ushort_t* At = (ushort_t*)smem_raw;        // [128][64]
    ushort_t* Bt = At + 128 * 64;              // [128][64]
    ushort_t* Ct = (ushort_t*)smem_raw;        // [128][stride 136] overlay
    int which = blockIdx.z;
    const ushort_t* W = Wb + ((size_t)which << 20);
    int m0 = blockIdx.y * 128, n0 = blockIdx.x * 128;
    int t = threadIdx.x, lane = t & 63, wave = t >> 6;
    int quad = lane >> 4, l16 = lane & 15;
    int wr = (wave >> 1) * 64, wc = (wave & 1) * 64;
    f32x4 acc[4][4] = {};
    for (int k0 = 0; k0 < 1024; k0 += 64) {
        for (int r = 0; r < 4; r++) {
            int idx = r * 256 + t;
            int row = idx >> 3, co = (idx & 7) * 8;
            gld_lds16(Ab + (size_t)(m0 + row) * 1024 + k0 + co, At + idx * 8);
            gld_lds16(W + (size_t)(n0 + row) * 1024 + k0 + co, Bt + idx * 8);
        }
        asm volatile("s_waitcnt vmcnt(0)" ::: "memory");
        __syncthreads();
        for (int kk = 0; kk < 2; kk++) {
            bf16x8 af[4], bf[4];
            for (int i = 0; i < 4; i++)
                af[i] = *(const bf16x8*)(At + (wr + i * 16 + l16) * 64 + kk * 32 + quad * 8);
            for (int j = 0; j < 4; j++)
                bf[j] = *(const bf16x8*)(Bt + (wc + j * 16 + l16) * 64 + kk * 32 + quad * 8);
            for (int i = 0; i < 4; i++)
                for (int j = 0; j < 4; j++)
                    acc[i][j] = MFMA16(af[i], bf[j], acc[i][j]);
        }
        __syncthreads();
    }
    const float* bias = which == 0 ? bq : (which == 1 ? bk : bv);
    float sc = which == 0 ? (0.125f * 1.44269504f) : 1.0f;  // 1/sqrt(HD)*log2e
    if (which == 2) {
        for (int j = 0; j < 4; j++) {
            float bias_v = bias[n0 + wc + j * 16 + l16];
            for (int i = 0; i < 4; i++) {
                ushort4 pk;
                pk.x = f2b(acc[i][j].x + bias_v);
                pk.y = f2b(acc[i][j].y + bias_v);
                pk.z = f2b(acc[i][j].z + bias_v);
                pk.w = f2b(acc[i][j].w + bias_v);
                *(ushort4*)(Ct + (wc + j * 16 + l16) * 136 + wr + i * 16 + quad * 4) = pk;
            }
        }
    } else {
        for (int j = 0; j < 4; j++) {
            float bias_v = bias[n0 + wc + j * 16 + l16];
            int col = wc + j * 16 + l16;
            for (int i = 0; i < 4; i++) {
                int rb = wr + i * 16 + quad * 4;
                Ct[(rb + 0) * 136 + col] = f2b((acc[i][j].x + bias_v) * sc);
                Ct[(rb + 1) * 136 + col] = f2b((acc[i][j].y + bias_v) * sc);
                Ct[(rb + 2) * 136 + col] = f2b((acc[i][j].z + bias_v) * sc);
                Ct[(rb + 3) * 136 + col] = f2b((acc[i][j].w + bias_v) * sc);
            }
        }
    }
    __syncthreads();
    for (int r = 0; r < 8; r++) {
        int idx = r * 256 + t;
        int row = idx >> 4, c8 = (idx & 15) * 8;
        uint4 val = *(const uint4*)(Ct + row * 136 + c8);
        if (which == 2) {
            int col = n0 + row, h = col >> 6, d = col & 63;
            int tok = m0 + c8, b = tok >> 11, s = tok & 2047;
            *(uint4*)(vt_ws + ((size_t)(b * 16 + h) * 64 + d) * 2048 + s) = val;
        } else {
            int tok = m0 + row, b = tok >> 11, s = tok & 2047;
            int col = n0 + c8, h = col >> 6, d = col & 63;
            ushort_t* base = which == 0 ? q_ws : k_ws;
            *(uint4*)(base + ((size_t)(b * 16 + h) * 2048 + s) * 64 + d) = val;
        }
    }
}

// ---------------- flash attention: 2-tile ILP, quad-buffer, 1 barrier/round -
__global__ __launch_bounds__(256, 2) void attn_k(
    const ushort_t* __restrict__ q_ws, const ushort_t* __restrict__ k_ws,
    const ushort_t* __restrict__ vt_ws, const float* __restrict__ mask,
    float* __restrict__ out) {
    // 4 buffers of 16KB (Kl 64x64 8KB + Vtl 64x64 8KB, mod-8 xor-swizzle),
    // mask f32[2048] at +65536. Epilogue overlay Ow[128][65] over buf 0/1.
    __shared__ __align__(16) char smraw[73728];
    float* Ml = (float*)(smraw + 65536);
    float* Ow = (float*)smraw;

    int bh = blockIdx.y, b = bh >> 4, h = bh & 15;
    int q0 = blockIdx.x * 256;
    int t = threadIdx.x, lane = t & 63, w = t >> 6;
    int l31 = lane & 31, hi = lane >> 5;
    bool h0 = (hi == 0);
    const ushort_t* Q = q_ws + (size_t)bh * 2048 * 64;
    const ushort_t* K = k_ws + (size_t)bh * 2048 * 64;
    const ushort_t* Vt = vt_ws + (size_t)bh * 64 * 2048;

    for (int r = 0; r < 8; r++) {
        int i = r * 256 + t;
        Ml[i] = mask[b * 2048 + i] * 1.44269504f;
    }

    bf16x8 qf[2][4];
#pragma unroll
    for (int qg = 0; qg < 2; qg++)
#pragma unroll
        for (int cs = 0; cs < 4; cs++)
            qf[qg][cs] = *(const bf16x8*)(
                Q + (size_t)(q0 + w * 64 + qg * 32 + l31) * 64 + cs * 16 + hi * 8);
    int co[4];
#pragma unroll
    for (int cs = 0; cs < 4; cs++) co[cs] = ((cs * 2 + hi) ^ (l31 & 7)) * 8;

    f32x16 o00 = {}, o01 = {}, o10 = {}, o11 = {};
    float rs0 = 0.f, rs1 = 0.f;

    auto stage = [&](int bufi, int t0) {
        ushort_t* Klb = (ushort_t*)(smraw + bufi * 16384);
        ushort_t* Vtlb = Klb + 4096;
#pragma unroll
        for (int it = 0; it < 2; it++) {
            int idx = it * 256 + t;
            int row = idx >> 3, ch = idx & 7;
            int sch = (ch ^ (row & 7)) * 8;
            gld_lds16(K + (size_t)(t0 + row) * 64 + sch, Klb + idx * 8);
            gld_lds16(Vt + (size_t)row * 2048 + t0 + sch, Vtlb + idx * 8);
        }
    };

    // softmax for one 64-key tile, one q-group: consumes s-pair, emits pfr[4]
    auto smax = [&](const f32x16& sa, const f32x16& sb, int moff,
                    bf16x8* pf) -> float {
        u32 pa[8], pb[8];
        float rst = 0.f;
#pragma unroll
        for (int i = 0; i < 4; i++) {
            f32x4 bm = *(const f32x4*)(Ml + moff + 8 * i + 4 * hi);
            float e0 = fexp2(sa[4 * i + 0] + bm[0]);
            float e1 = fexp2(sa[4 * i + 1] + bm[1]);
            float e2 = fexp2(sa[4 * i + 2] + bm[2]);
            float e3 = fexp2(sa[4 * i + 3] + bm[3]);
            rst += (e0 + e1) + (e2 + e3);
            pa[2 * i] = pkpair(e0, e1);
            pa[2 * i + 1] = pkpair(e2, e3);
        }
#pragma unroll
        for (int i = 0; i < 4; i++) {
            f32x4 bm = *(const f32x4*)(Ml + moff + 32 + 8 * i + 4 * hi);
            float e0 = fexp2(sb[4 * i + 0] + bm[0]);
            float e1 = fexp2(sb[4 * i + 1] + bm[1]);
            float e2 = fexp2(sb[4 * i + 2] + bm[2]);
            float e3 = fexp2(sb[4 * i + 3] + bm[3]);
            rst += (e0 + e1) + (e2 + e3);
            pb[2 * i] = pkpair(e0, e1);
            pb[2 * i + 1] = pkpair(e2, e3);
        }
#pragma unroll
        for (int g = 0; g < 4; g++) {
            const u32* aa = (g < 2) ? pa : pb;
            int base = (g & 1) * 4;
            u32 y0 = h0 ? aa[base + 2] : aa[base + 0];
            u32 y1 = h0 ? aa[base + 3] : aa[base + 1];
            u32 sy0 = (u32)__shfl_xor((int)y0, 32, 64);
            u32 sy1 = (u32)__shfl_xor((int)y1, 32, 64);
            pf[g] = mk8(h0 ? aa[base + 0] : sy0, h0 ? aa[base + 1] : sy1,
                        h0 ? sy0 : aa[base + 2], h0 ? sy1 : aa[base + 3]);
        }
        return rst;
    };

    stage(0, 0);
    stage(1, 64);
    asm volatile("s_waitcnt vmcnt(0)" ::: "memory");
    __syncthreads();
    int pair = 0;
    for (int t0 = 0; t0 < 2048; t0 += 128) {
        // prefetch next round's two tiles into the other buffer pair
        if (t0 + 128 < 2048) {
            stage((pair ^ 1) * 2 + 0, t0 + 128);
            stage((pair ^ 1) * 2 + 1, t0 + 192);
        }
        const ushort_t* KlA = (const ushort_t*)(smraw + (pair * 2 + 0) * 16384);
        const ushort_t* VtlA = KlA + 4096;
        const ushort_t* KlB = (const ushort_t*)(smraw + (pair * 2 + 1) * 16384);
        const ushort_t* VtlB = KlB + 4096;

        // ---- QK tile A ----
        f32x16 a00 = {}, a01 = {}, a10 = {}, a11 = {};
#pragma unroll
        for (int cs = 0; cs < 4; cs++) {
            bf16x8 k0 = *(const bf16x8*)(KlA + l31 * 64 + co[cs]);
            bf16x8 k1 = *(const bf16x8*)(KlA + (32 + l31) * 64 + co[cs]);
            a00 = MFMA32(k0, qf[0][cs], a00);
            a01 = MFMA32(k1, qf[0][cs], a01);
            a10 = MFMA32(k0, qf[1][cs], a10);
            a11 = MFMA32(k1, qf[1][cs], a11);
        }
        // ---- softmax A (S_A dies into pfrA) ----
        bf16x8 pfrA[2][4];
        rs0 += smax(a00, a01, t0, pfrA[0]);
        rs1 += smax(a10, a11, t0, pfrA[1]);
        // ---- QK tile B (MFMA/LDS overlaps softmax A in scheduler) ----
        f32x16 b00 = {}, b01 = {}, b10 = {}, b11 = {};
#pragma unroll
        for (int cs = 0; cs < 4; cs++) {
            bf16x8 k0 = *(const bf16x8*)(KlB + l31 * 64 + co[cs]);
            bf16x8 k1 = *(const bf16x8*)(KlB + (32 + l31) * 64 + co[cs]);
            b00 = MFMA32(k0, qf[0][cs], b00);
            b01 = MFMA32(k1, qf[0][cs], b01);
            b10 = MFMA32(k0, qf[1][cs], b10);
            b11 = MFMA32(k1, qf[1][cs], b11);
        }
        // ---- PV tile A ----
#pragma unroll
        for (int cs = 0; cs < 4; cs++) {
            bf16x8 v0 = *(const bf16x8*)(VtlA + l31 * 64 + co[cs]);
            bf16x8 v1 = *(const bf16x8*)(VtlA + (32 + l31) * 64 + co[cs]);
            o00 = MFMA32(v0, pfrA[0][cs], o00);
            o01 = MFMA32(v1, pfrA[0][cs], o01);
            o10 = MFMA32(v0, pfrA[1][cs], o10);
            o11 = MFMA32(v1, pfrA[1][cs], o11);
        }
        // ---- softmax B ----
        bf16x8 pfrB[2][4];
        rs0 += smax(b00, b01, t0 + 64, pfrB[0]);
        rs1 += smax(b10, b11, t0 + 64, pfrB[1]);
        // ---- PV tile B ----
#pragma unroll
        for (int cs = 0; cs < 4; cs++) {
            bf16x8 v0 = *(const bf16x8*)(VtlB + l31 * 64 + co[cs]);
            bf16x8 v1 = *(const bf16x8*)(VtlB + (32 + l31) * 64 + co[cs]);
            o00 = MFMA32(v0, pfrB[0][cs], o00);
            o01 = MFMA32(v1, pfrB[0][cs], o01);
            o10 = MFMA32(v0, pfrB[1][cs], o10);
            o11 = MFMA32(v1, pfrB[1][cs], o11);
        }
        __syncthreads();
        pair ^= 1;
    }
    rs0 += __shfl_xor(rs0, 32, 64);
    rs1 += __shfl_xor(rs1, 32, 64);
    float inv0 = 1.f / rs0, inv1 = 1.f / rs1;
    // epilogue: per q-group, O^T -> LDS transpose -> coalesced f32x4 stores
#pragma unroll
    for (int qg = 0; qg < 2; qg++) {
        float inv = qg ? inv1 : inv0;
        const f32x16& a0 = qg ? o10 : o00;
        const f32x16& a1 = qg ? o11 : o01;
#pragma unroll
        for (int g = 0; g < 4; g++) {
            f32x4 c0, c1;
#pragma unroll
            for (int r = 0; r < 4; r++) {
                c0[r] = a0[4 * g + r] * inv;
                c1[r] = a1[4 * g + r] * inv;
            }
            *(f32x4*)(Ow + (w * 32 + l31) * 65 + 8 * g + 4 * hi) = c0;
            *(f32x4*)(Ow + (w * 32 + l31) * 65 + 32 + 8 * g + 4 * hi) = c1;
        }
        __syncthreads();
#pragma unroll
        for (int cc = 0; cc < 8; cc++) {
            int c = cc * 256 + t;
            int row = c >> 4, seg = (c & 15) * 4;
            f32x4 vv = *(const f32x4*)(Ow + row * 65 + seg);
            int ql = (row >> 5) * 64 + qg * 32 + (row & 31);
            *(f32x4*)(out + ((size_t)(b * 2048 + q0 + ql)) * 1024 + h * 64 + seg) = vv;
        }
        __syncthreads();
    }
}

extern "C" void kernel_launch(void* const* d_in, const int* in_sizes, int n_in,
                              void* d_out, int out_size, void* d_ws, size_t ws_size,
                              hipStream_t stream) {
    const float* hs = (const float*)d_in[0];
    const float* mask = (const float*)d_in[1];
    const float* wq = (const float*)d_in[2];
    const float* bq = (const float*)d_in[3];
    const float* wk = (const float*)d_in[4];
    const float* bk = (const float*)d_in[5];
    const float* wv = (const float*)d_in[6];
    const float* bv = (const float*)d_in[7];
    float* out = (float*)d_out;
    char* ws = (char*)d_ws;
    ushort_t* hs_b = (ushort_t*)ws;
    ushort_t* w_b = (ushort_t*)(ws + 16777216);
    ushort_t* q_ws = (ushort_t*)(ws + 23068672);
    ushort_t* k_ws = (ushort_t*)(ws + 39845888);
    ushort_t* vt_ws = (ushort_t*)(ws + 56623104);

    convert_k<<<5632, 256, 0, stream>>>(hs, wq, wk, wv, hs_b, w_b);
    qkv_gemm<<<dim3(8, 64, 3), 256, 0, stream>>>(hs_b, w_b, bq, bk, bv, q_ws, k_ws, vt_ws);
    attn_k<<<dim3(8, 64), 256, 0, stream>>>(q_ws, k_ws, vt_ws, mask, out);
}